// Round 4
// baseline (232.425 us; speedup 1.0000x reference)
//
#include <hip/hip_runtime.h>

// SetNorm: B=64, N=2048, D=256 fp32.
// out[b,n,d] = n < len[b] ? ((x[b,n,d] - mean_b) / (sqrt(var_b) + eps)) * w[d] + bias[d] : 0
//
// R8: write/read direction overlap. K1 does stats for valid rows AND
// nontemporal zero-fill for invalid rows (each block moves exactly 64 KB ->
// per-CU traffic is constant, perfectly balanced). K2 touches ONLY valid rows
// (write ~67 MB instead of 134 MB) and re-reduces the 32 partials in its
// prologue (finalize kernel dropped; 2 launches total). Striped 4-row groups
// keep validity wave-uniform and per-block work ~len/N.

#define BB 64
#define NN 2048
#define DD 256
#define EPSV 1e-5f
#define CHUNKS 32                 // K1 blocks per batch
#define GROUPS (NN / 4)           // 512 4-row groups per batch
#define BAT4 (NN * DD / 4)        // 131072 f32x4 per batch
#define K2_BPB 128                // K2 blocks per batch (4 groups each)

typedef float f32x4 __attribute__((ext_vector_type(4)));

// ---------- Kernel 1: stats over valid rows + zero-fill invalid rows ----------
// Chunk c of batch b owns groups g = c + 32k, k = 0..15.
//   g <  len/4          : fully valid  -> read + accumulate
//   g == len/4 (if len%4): boundary    -> valid rows acc, invalid rows zeroed
//   g >= ceil(len/4)    : fully invalid-> zero-store 4 KB
// Every block moves exactly 16 groups x 4 KB = 64 KB regardless of len.
__global__ __launch_bounds__(256) void setnorm_pass1(
    const float* __restrict__ x, const int* __restrict__ lengths,
    float* __restrict__ partials, float* __restrict__ out) {
  const int c = blockIdx.x;
  const int b = blockIdx.y;
  const int len = lengths[b];
  const int tRow = threadIdx.x >> 6;      // row within group (0..3)
  const f32x4* px = (const f32x4*)x + (size_t)b * BAT4;
  f32x4* po = (f32x4*)out + (size_t)b * BAT4;

  const int gFull = len >> 2;             // g < gFull: fully valid
  const int g4 = (len + 3) >> 2;          // g >= g4: fully invalid
  int nFull = (gFull - c + 31) >> 5; if (nFull < 0) nFull = 0;
  int kZ = (g4 - c + 31) >> 5;       if (kZ < 0) kZ = 0;

  float sum = 0.f, sumsq = 0.f;
  // fully-valid groups: unconditional coalesced loads
  #pragma unroll 4
  for (int k = 0; k < nFull; ++k) {
    const int g = c + (k << 5);
    const f32x4 v = px[g * 256 + threadIdx.x];
    sum += v.x + v.y + v.z + v.w;
    sumsq += v.x * v.x + v.y * v.y + v.z * v.z + v.w * v.w;
  }
  // boundary group (at most one chunk owns it): mask acc / zero invalid rows
  if ((len & 3) && ((gFull & 31) == c)) {
    const int idx = gFull * 256 + threadIdx.x;
    const int row = (gFull << 2) + tRow;  // wave-uniform validity
    if (row < len) {
      const f32x4 v = px[idx];
      sum += v.x + v.y + v.z + v.w;
      sumsq += v.x * v.x + v.y * v.y + v.z * v.z + v.w * v.w;
    } else {
      const f32x4 z = {0.f, 0.f, 0.f, 0.f};
      __builtin_nontemporal_store(z, po + idx);
    }
  }
  // fully-invalid groups: nontemporal zero-fill
  {
    const f32x4 z = {0.f, 0.f, 0.f, 0.f};
    #pragma unroll 4
    for (int k = kZ; k < 16; ++k) {
      const int g = c + (k << 5);
      __builtin_nontemporal_store(z, po + g * 256 + threadIdx.x);
    }
  }

  #pragma unroll
  for (int off = 32; off > 0; off >>= 1) {
    sum += __shfl_down(sum, off, 64);
    sumsq += __shfl_down(sumsq, off, 64);
  }
  __shared__ float ssum[4], ssq[4];
  const int wave = threadIdx.x >> 6;
  const int lane = threadIdx.x & 63;
  if (lane == 0) { ssum[wave] = sum; ssq[wave] = sumsq; }
  __syncthreads();
  if (threadIdx.x == 0) {
    const float ts = ssum[0] + ssum[1] + ssum[2] + ssum[3];
    const float tq = ssq[0] + ssq[1] + ssq[2] + ssq[3];
    partials[(b * CHUNKS + c) * 2 + 0] = ts;
    partials[(b * CHUNKS + c) * 2 + 1] = tq;
  }
}

// ---------- Kernel 2: finalize stats in prologue + normalize valid rows ----
// Block (b, j) owns groups g = j + 128*i, i = 0..3. If 4j >= len the whole
// block range is invalid (already zeroed by K1) -> immediate exit.
__global__ __launch_bounds__(256) void setnorm_pass2(
    const float* __restrict__ x, const int* __restrict__ lengths,
    const float* __restrict__ weights, const float* __restrict__ biases,
    const float* __restrict__ partials, float* __restrict__ out) {
  const int blk = blockIdx.x;
  const int b = blk >> 7;                 // 128 blocks per batch
  const int j = blk & 127;
  const int len = lengths[b];
  if ((j << 2) >= len) return;            // nothing valid in this block

  __shared__ float s_mean, s_inv;
  if (threadIdx.x < 64) {
    float s = 0.f, q = 0.f;
    if (threadIdx.x < CHUNKS) {           // 64 B, L2/L3-hot
      s = partials[(b * CHUNKS + threadIdx.x) * 2 + 0];
      q = partials[(b * CHUNKS + threadIdx.x) * 2 + 1];
    }
    #pragma unroll
    for (int off = 16; off > 0; off >>= 1) {
      s += __shfl_down(s, off, 64);
      q += __shfl_down(q, off, 64);
    }
    if (threadIdx.x == 0) {
      const float denom = (float)len * (float)DD;
      const float mean = s / denom;
      float var = q / denom - mean * mean;
      var = fmaxf(var, 0.f);
      s_mean = mean;
      s_inv = 1.f / (sqrtf(var) + EPSV);
    }
  }
  __syncthreads();
  const float mean = s_mean;
  const float inv = s_inv;

  const int d4 = threadIdx.x & 63;        // feature f32x4 index
  const f32x4 w = ((const f32x4*)weights)[d4];
  const f32x4 bi = ((const f32x4*)biases)[d4];
  const int tRow = threadIdx.x >> 6;

  const f32x4* px = (const f32x4*)x + (size_t)b * BAT4;
  f32x4* po = (f32x4*)out + (size_t)b * BAT4;
  #pragma unroll
  for (int i = 0; i < 4; ++i) {
    const int g = j + (i << 7);           // strided group
    const int idx4 = g * 256 + threadIdx.x;
    const int row = (g << 2) + tRow;      // wave-uniform validity
    if (row < len) {                      // invalid rows already zeroed by K1
      const f32x4 v = px[idx4];
      f32x4 o;
      o.x = (v.x - mean) * inv * w.x + bi.x;
      o.y = (v.y - mean) * inv * w.y + bi.y;
      o.z = (v.z - mean) * inv * w.z + bi.z;
      o.w = (v.w - mean) * inv * w.w + bi.w;
      __builtin_nontemporal_store(o, po + idx4);
    }
  }
}

extern "C" void kernel_launch(void* const* d_in, const int* in_sizes, int n_in,
                              void* d_out, int out_size, void* d_ws, size_t ws_size,
                              hipStream_t stream) {
  const float* x = (const float*)d_in[0];
  const int* lengths = (const int*)d_in[1];
  const float* weights = (const float*)d_in[2];
  const float* biases = (const float*)d_in[3];
  float* out = (float*)d_out;

  float* partials = (float*)d_ws;         // B*CHUNKS*2 floats = 16 KB

  dim3 g1(CHUNKS, BB);                    // 2048 blocks, 64 KB traffic each
  setnorm_pass1<<<g1, 256, 0, stream>>>(x, lengths, partials, out);
  setnorm_pass2<<<BB * K2_BPB, 256, 0, stream>>>(x, lengths, weights, biases,
                                                 partials, out);
}